// Round 3
// baseline (104.865 us; speedup 1.0000x reference)
//
#include <hip/hip_runtime.h>

// CausalGraphLayer: out[b,n,t,c] = tanh( sum_k z[b, idx[n,k], t, c] * w[n,k,c] )
//   w[n,k,c] = adj[n,k] * sum_bb cc[c,bb] * bw[bb,n,k]
// B=2, N=2048, T=32, C=32, NBASE=4, MAXK=32, KC=16.
//
// R3: LDS-resident gather. Kernel1 precomputes w as bf16 into d_ws
// (layout [cq][n][k][8c], 2 MB, L2-resident). Kernel2: block = (b,t,cq,s);
// stages z[b,:,t,cq*8..+8) (64 KB fp32) into LDS as two float4 SoA planes,
// then gathers neighbors from LDS instead of L2/L3.

constexpr int BB_    = 2;
constexpr int NN_    = 2048;
constexpr int TT_    = 32;
constexpr int CC_    = 32;
constexpr int NBASE_ = 4;
constexpr int MAXK_  = 32;
constexpr int KC_    = 16;

__device__ __forceinline__ float fast_tanh(float x) {
    float e = __expf(2.0f * x);
    float r = __builtin_amdgcn_rcpf(e + 1.0f);
    return fmaf(-2.0f, r, 1.0f);
}

__device__ __forceinline__ unsigned pack_bf16(float x, float y) {
    unsigned ux = __float_as_uint(x), uy = __float_as_uint(y);
    ux = (ux + 0x7fffu + ((ux >> 16) & 1u)) >> 16;   // RNE
    uy = (uy + 0x7fffu + ((uy >> 16) & 1u)) >> 16;
    return ux | (uy << 16);
}
__device__ __forceinline__ float blo(unsigned u) { return __uint_as_float(u << 16); }
__device__ __forceinline__ float bhi(unsigned u) { return __uint_as_float(u & 0xffff0000u); }

// ---------------- kernel 1: w16[cq][n][k][8c] bf16 (2 MB in d_ws) -------------
__global__ __launch_bounds__(512) void prep_w(
    const float* __restrict__ adj,   // [N][MAXK]
    const float* __restrict__ bw,    // [NBASE][N][MAXK]
    const float* __restrict__ cc,    // [C][NBASE]
    uint4*       __restrict__ w16)   // [4][N][KC] uint4 (16 B per (cq,n,k))
{
    const int gid = blockIdx.x * 512 + threadIdx.x;   // 32768 = N*KC
    const int n = gid >> 4, k = gid & 15;

    const float a  = adj[n * MAXK_ + k];
    const float b0 = bw[(0 * NN_ + n) * MAXK_ + k];
    const float b1 = bw[(1 * NN_ + n) * MAXK_ + k];
    const float b2 = bw[(2 * NN_ + n) * MAXK_ + k];
    const float b3 = bw[(3 * NN_ + n) * MAXK_ + k];

    #pragma unroll
    for (int cq = 0; cq < 4; ++cq) {
        unsigned u[4];
        #pragma unroll
        for (int j = 0; j < 4; ++j) {
            int c0 = cq * 8 + 2 * j;
            float w0 = a * (cc[c0 * 4 + 0] * b0 + cc[c0 * 4 + 1] * b1 +
                            cc[c0 * 4 + 2] * b2 + cc[c0 * 4 + 3] * b3);
            float w1 = a * (cc[(c0 + 1) * 4 + 0] * b0 + cc[(c0 + 1) * 4 + 1] * b1 +
                            cc[(c0 + 1) * 4 + 2] * b2 + cc[(c0 + 1) * 4 + 3] * b3);
            u[j] = pack_bf16(w0, w1);
        }
        w16[((size_t)cq * NN_ + n) * KC_ + k] = make_uint4(u[0], u[1], u[2], u[3]);
    }
}

// ---------------- kernel 2: LDS-resident gather ------------------------------
__global__ __launch_bounds__(512, 4) void cgl_main(
    const float* __restrict__ z,     // [B][N][T][C]
    const int*   __restrict__ nbr,   // [N][KC]
    const uint4* __restrict__ w16,   // [4][N][KC]
    float*       __restrict__ out)   // [B][N][T][C]
{
    __shared__ float4 zl0[NN_];      // c cq*8+0..3, 32 KB
    __shared__ float4 zl1[NN_];      // c cq*8+4..7, 32 KB

    const int tid   = threadIdx.x;
    const int g     = blockIdx.x;    // 512 blocks
    const int bt    = g & 63;        // all 8 blocks of a (b,t) share g%8 = bt%8 -> one XCD
    const int inner = g >> 6;        // 0..7
    const int cq    = inner >> 1;
    const int s     = inner & 1;
    const int b     = bt >> 5;
    const int t     = bt & 31;

    // ---- stage z[b, :, t, cq*8 .. cq*8+8) into LDS (fp32, SoA float4 planes) ----
    const float* zbase = z + ((size_t)b * NN_ * TT_ + t) * CC_ + cq * 8;
    #pragma unroll
    for (int r = 0; r < 4; ++r) {
        int n = r * 512 + tid;
        const float4* p = (const float4*)(zbase + (size_t)n * (TT_ * CC_));
        zl0[n] = p[0];
        zl1[n] = p[1];
    }
    __syncthreads();

    // ---- gather-accumulate: thread owns (n, 8 c's); n-half selected by s ----
    #pragma unroll
    for (int r = 0; r < 2; ++r) {
        const int n = s * 1024 + r * 512 + tid;

        const int4* ip = (const int4*)(nbr + n * KC_);
        int4 i0 = ip[0], i1 = ip[1], i2 = ip[2], i3 = ip[3];
        int idxs[16] = { i0.x, i0.y, i0.z, i0.w,  i1.x, i1.y, i1.z, i1.w,
                         i2.x, i2.y, i2.z, i2.w,  i3.x, i3.y, i3.z, i3.w };

        const uint4* wp = w16 + ((size_t)cq * NN_ + n) * KC_;  // 16 contiguous uint4

        float acc0 = 0.f, acc1 = 0.f, acc2 = 0.f, acc3 = 0.f;
        float acc4 = 0.f, acc5 = 0.f, acc6 = 0.f, acc7 = 0.f;

        #pragma unroll
        for (int k = 0; k < KC_; ++k) {
            const uint4 wv = wp[k];
            const int nk = idxs[k];
            const float4 za = zl0[nk];   // ds_read_b128, bank-group = nk % 8
            const float4 zb = zl1[nk];
            acc0 = fmaf(za.x, blo(wv.x), acc0);
            acc1 = fmaf(za.y, bhi(wv.x), acc1);
            acc2 = fmaf(za.z, blo(wv.y), acc2);
            acc3 = fmaf(za.w, bhi(wv.y), acc3);
            acc4 = fmaf(zb.x, blo(wv.z), acc4);
            acc5 = fmaf(zb.y, bhi(wv.z), acc5);
            acc6 = fmaf(zb.z, blo(wv.w), acc6);
            acc7 = fmaf(zb.w, bhi(wv.w), acc7);
        }

        float4 o0, o1;
        o0.x = fast_tanh(acc0); o0.y = fast_tanh(acc1);
        o0.z = fast_tanh(acc2); o0.w = fast_tanh(acc3);
        o1.x = fast_tanh(acc4); o1.y = fast_tanh(acc5);
        o1.z = fast_tanh(acc6); o1.w = fast_tanh(acc7);

        float* op = out + ((size_t)(b * NN_ + n) * TT_ + t) * CC_ + cq * 8;
        ((float4*)op)[0] = o0;
        ((float4*)op)[1] = o1;
    }
}

extern "C" void kernel_launch(void* const* d_in, const int* in_sizes, int n_in,
                              void* d_out, int out_size, void* d_ws, size_t ws_size,
                              hipStream_t stream) {
    const float* z   = (const float*)d_in[0];
    const int*   nbr = (const int*)d_in[1];
    const float* adj = (const float*)d_in[2];
    const float* bw  = (const float*)d_in[3];
    const float* cc  = (const float*)d_in[4];
    float* out  = (float*)d_out;
    uint4* w16  = (uint4*)d_ws;      // 2 MB of ws

    prep_w<<<dim3(NN_ * KC_ / 512), dim3(512), 0, stream>>>(adj, bw, cc, w16);
    cgl_main<<<dim3(512), dim3(512), 0, stream>>>(z, nbr, w16, out);
}

// Round 4
// 96.000 us; speedup vs baseline: 1.0923x; 1.0923x over previous
//
#include <hip/hip_runtime.h>

// CausalGraphLayer: out[b,n,t,c] = tanh( sum_k z[b, idx[n,k], t, c] * w[n,k,c] )
//   w[n,k,c] = adj[n,k] * sum_bb cc[c,bb] * bw[bb,n,k]
// B=2, N=2048, T=32, C=32, NBASE=4, MAXK=32, KC=16.
//
// R4: R1 structure (block = (b,n), w tile in LDS, contiguous 1KB wave gathers)
// + MLP fix: all 16 neighbor-row loads issued before any FMA (zv[16] batch),
// + scalar (SGPR) neighbor indices -> global_load saddr form, minimal VALU.

constexpr int BB_    = 2;
constexpr int NN_    = 2048;
constexpr int TT_    = 32;
constexpr int CC_    = 32;
constexpr int NBASE_ = 4;
constexpr int MAXK_  = 32;
constexpr int KC_    = 16;

__device__ __forceinline__ float fast_tanh(float x) {
    float e = __expf(2.0f * x);
    float r = __builtin_amdgcn_rcpf(e + 1.0f);
    return fmaf(-2.0f, r, 1.0f);
}

__global__ __launch_bounds__(256, 4) void cgl_kernel(
    const float* __restrict__ z,     // [B,N,T,C]
    const int*   __restrict__ nbr,   // [N,KC]
    const float* __restrict__ adj,   // [N,MAXK]
    const float* __restrict__ bw,    // [NBASE,N,MAXK]
    const float* __restrict__ cc,    // [C,NBASE]
    float*       __restrict__ out)   // [B,N,T,C]
{
    __shared__ __align__(16) float w_s[KC_][CC_];   // 2 KB
    __shared__ float bw_s[NBASE_][KC_];             // 256 B
    __shared__ float cc_s[NBASE_][CC_];             // 512 B (transposed: [bb][c])
    __shared__ float adj_s[KC_];

    const int tid = threadIdx.x;
    const int blk = blockIdx.x;       // 0 .. B*N-1
    const int b   = blk >> 11;
    const int n   = blk & (NN_ - 1);

    // ---- stage small per-node tables into LDS (disjoint thread ranges) ----
    if (tid < NBASE_ * KC_) {                        // 64 threads: basis weights
        int bb = tid >> 4, k = tid & 15;
        bw_s[bb][k] = bw[((size_t)bb * NN_ + n) * MAXK_ + k];
    } else if (tid < 64 + NBASE_ * CC_) {            // 128 threads: cc transposed
        int i = tid - 64, bb = i >> 5, c = i & 31;
        cc_s[bb][c] = cc[c * NBASE_ + bb];
    } else if (tid >= 192 && tid < 192 + KC_) {      // 16 threads: adjacency
        int k = tid - 192;
        adj_s[k] = adj[(size_t)n * MAXK_ + k];
    }

    // ---- block-uniform neighbor indices -> SGPRs (scalar loads) ----
    const int* __restrict__ ip = nbr + n * KC_;
    int nks[KC_];
    #pragma unroll
    for (int k = 0; k < KC_; ++k)
        nks[k] = __builtin_amdgcn_readfirstlane(ip[k]);

    __syncthreads();

    // ---- compute w[k][c] = adj[k] * sum_bb cc[bb][c]*bw[bb][k]  (512 cells) ----
    {
        int i = tid;
        #pragma unroll
        for (int r = 0; r < 2; ++r, i += 256) {
            int k = i >> 5, c = i & 31;
            float s = cc_s[0][c] * bw_s[0][k]
                    + cc_s[1][c] * bw_s[1][k]
                    + cc_s[2][c] * bw_s[2][k]
                    + cc_s[3][c] * bw_s[3][k];
            w_s[k][c] = s * adj_s[k];
        }
    }

    // ---- issue ALL 16 gathers up front (16 outstanding vmem per wave) ----
    const float4* __restrict__ z4 =
        (const float4*)z + (size_t)b * NN_ * (TT_ * CC_ / 4);
    float4 zv[KC_];
    #pragma unroll
    for (int k = 0; k < KC_; ++k)
        zv[k] = z4[(size_t)nks[k] * (TT_ * CC_ / 4) + tid];  // saddr + tid, 1KB/wave

    __syncthreads();   // w_s ready (overlaps with loads in flight)

    // ---- FMA reduction ----
    const int c0 = (tid << 2) & 31;
    float4 acc = make_float4(0.f, 0.f, 0.f, 0.f);
    #pragma unroll
    for (int k = 0; k < KC_; ++k) {
        float4 wv = *(const float4*)&w_s[k][c0];   // 8-way broadcast, conflict-free
        acc.x = fmaf(zv[k].x, wv.x, acc.x);
        acc.y = fmaf(zv[k].y, wv.y, acc.y);
        acc.z = fmaf(zv[k].z, wv.z, acc.z);
        acc.w = fmaf(zv[k].w, wv.w, acc.w);
    }

    float4 o;
    o.x = fast_tanh(acc.x);
    o.y = fast_tanh(acc.y);
    o.z = fast_tanh(acc.z);
    o.w = fast_tanh(acc.w);
    ((float4*)out)[(size_t)blk * 256 + tid] = o;
}

extern "C" void kernel_launch(void* const* d_in, const int* in_sizes, int n_in,
                              void* d_out, int out_size, void* d_ws, size_t ws_size,
                              hipStream_t stream) {
    const float* z   = (const float*)d_in[0];
    const int*   nbr = (const int*)d_in[1];
    const float* adj = (const float*)d_in[2];
    const float* bw  = (const float*)d_in[3];
    const float* cc  = (const float*)d_in[4];
    float* out = (float*)d_out;

    cgl_kernel<<<dim3(BB_ * NN_), dim3(256), 0, stream>>>(z, nbr, adj, bw, cc, out);
}

// Round 5
// 90.823 us; speedup vs baseline: 1.1546x; 1.0570x over previous
//
#include <hip/hip_runtime.h>

// CausalGraphLayer: out[b,n,t,c] = tanh( sum_k z[b, idx[n,k], t, c] * w[n,k,c] )
//   w[n,k,c] = adj[n,k] * sum_bb cc[c,bb] * bw[bb,n,k]
// B=2, N=2048, T=32, C=32, NBASE=4, MAXK=32, KC=16.
//
// R5: gather-line reduction. Prepass converts z to bf16 in d_ws (8 MB).
// Main kernel = R2 structure (XCD-pinned (b,tq) t-quarter slices, block =
// 4 nodes x 4 waves, w tile fp32 in LDS) but gathers bf16 rows: 512 B /
// 4 cache lines per wave-gather instead of 1 KB / 8 — halves the per-CU
// L1-miss (MSHR) load that R4 showed to be the binding constraint.

constexpr int BB_    = 2;
constexpr int NN_    = 2048;
constexpr int TT_    = 32;
constexpr int CC_    = 32;
constexpr int NBASE_ = 4;
constexpr int MAXK_  = 32;
constexpr int KC_    = 16;

constexpr int TQ_      = 4;                  // t-quarters
constexpr int NODES_PB = 4;                  // nodes per block (1 per wave)
constexpr int PLANE_   = TT_ * CC_;          // 1024 elems per (b,n)
constexpr int SLICE_   = (TT_ / TQ_) * CC_;  // 256 elems per (n, tq)

__device__ __forceinline__ float fast_tanh(float x) {
    float e = __expf(2.0f * x);
    float r = __builtin_amdgcn_rcpf(e + 1.0f);
    return fmaf(-2.0f, r, 1.0f);
}

__device__ __forceinline__ unsigned pack_bf16(float x, float y) {
    unsigned ux = __float_as_uint(x), uy = __float_as_uint(y);
    ux = (ux + 0x7fffu + ((ux >> 16) & 1u)) >> 16;   // RNE
    uy = (uy + 0x7fffu + ((uy >> 16) & 1u)) >> 16;
    return ux | (uy << 16);
}
__device__ __forceinline__ float blo(unsigned u) { return __uint_as_float(u << 16); }
__device__ __forceinline__ float bhi(unsigned u) { return __uint_as_float(u & 0xffff0000u); }

// ---------------- kernel 1: z (fp32, 16 MB) -> zb16 (bf16, 8 MB in d_ws) ----
__global__ __launch_bounds__(256) void z_to_bf16(
    const float4* __restrict__ z4, uint4* __restrict__ zb)
{
    const int gid = blockIdx.x * 256 + threadIdx.x;    // 524288 threads x 8 floats
    float4 a = z4[2 * gid];
    float4 b = z4[2 * gid + 1];
    zb[gid] = make_uint4(pack_bf16(a.x, a.y), pack_bf16(a.z, a.w),
                         pack_bf16(b.x, b.y), pack_bf16(b.z, b.w));
}

// ---------------- kernel 2: main gather ------------------------------------
__global__ __launch_bounds__(256, 4) void cgl_kernel(
    const unsigned short* __restrict__ zb,  // [B][N][T][C] bf16
    const int*   __restrict__ nbr,   // [N,KC]
    const float* __restrict__ adj,   // [N,MAXK]
    const float* __restrict__ bw,    // [NBASE,N,MAXK]
    const float* __restrict__ cc,    // [C,NBASE]
    float*       __restrict__ out)   // [B,N,T,C]
{
    __shared__ __align__(16) float w_s[NODES_PB][KC_][CC_];  // 8 KB
    __shared__ float bw_s[NODES_PB][NBASE_][KC_];            // 1 KB
    __shared__ float cc_s[NBASE_][CC_];                      // 512 B (transposed)
    __shared__ float adj_s[NODES_PB][KC_];

    const int tid = threadIdx.x;
    const int blk = blockIdx.x;

    // XCD-pinned (b, tq): blk % 8 -> XCD; per-XCD bf16 working set = 1 MB.
    const int xcd   = blk & 7;
    const int b     = xcd >> 2;
    const int tq    = xcd & 3;
    const int group = blk >> 3;          // 0..511
    const int node0 = group * NODES_PB;

    // ---- stage per-node tables ----
    {   // bw: 256 values, one per thread
        int nd = tid >> 6, bb = (tid >> 4) & 3, k = tid & 15;
        bw_s[nd][bb][k] = bw[((size_t)bb * NN_ + (node0 + nd)) * MAXK_ + k];

        if (tid < 64) {                          // adj
            int nd2 = tid >> 4, k2 = tid & 15;
            adj_s[nd2][k2] = adj[(size_t)(node0 + nd2) * MAXK_ + k2];
        } else if (tid < 192) {                  // cc transposed [bb][c]
            int i = tid - 64, bb2 = i >> 5, c2 = i & 31;
            cc_s[bb2][c2] = cc[c2 * NBASE_ + bb2];
        }
    }

    // ---- per-wave SGPR neighbor indices ----
    const int wave = tid >> 6;
    const int lane = tid & 63;
    const int n    = node0 + wave;
    const int* __restrict__ ip = nbr + n * KC_;
    int nks[KC_];
    #pragma unroll
    for (int k = 0; k < KC_; ++k)
        nks[k] = __builtin_amdgcn_readfirstlane(ip[k]);

    __syncthreads();

    // ---- compute w[nd][k][c]: 2048 cells, 8 per thread ----
    {
        int i = tid;
        #pragma unroll
        for (int r = 0; r < 8; ++r, i += 256) {
            int nd = i >> 9, k = (i >> 5) & 15, c = i & 31;
            float s = cc_s[0][c] * bw_s[nd][0][k]
                    + cc_s[1][c] * bw_s[nd][1][k]
                    + cc_s[2][c] * bw_s[nd][2][k]
                    + cc_s[3][c] * bw_s[nd][3][k];
            w_s[nd][k][c] = s * adj_s[nd][k];
        }
    }

    // ---- issue all 16 bf16 gathers (512 B / 4 lines per wave-instr) ----
    // lane owns 4 c's at one t: elem offset within slice = lane*4
    uint2 zv[KC_];
    {
        const size_t sbase = (size_t)b * NN_ * PLANE_ + (size_t)tq * SLICE_;
        #pragma unroll
        for (int k = 0; k < KC_; ++k) {
            const unsigned short* row = zb + sbase + (size_t)nks[k] * PLANE_;
            zv[k] = ((const uint2*)row)[lane];
        }
    }

    __syncthreads();   // w_s ready (gathers still in flight)

    // ---- FMA reduction ----
    const int c0 = (lane & 7) << 2;
    float4 acc = make_float4(0.f, 0.f, 0.f, 0.f);
    #pragma unroll
    for (int k = 0; k < KC_; ++k) {
        float4 wv = *(const float4*)&w_s[wave][k][c0];   // broadcast, conflict-free
        acc.x = fmaf(blo(zv[k].x), wv.x, acc.x);
        acc.y = fmaf(bhi(zv[k].x), wv.y, acc.y);
        acc.z = fmaf(blo(zv[k].y), wv.z, acc.z);
        acc.w = fmaf(bhi(zv[k].y), wv.w, acc.w);
    }

    float4 o;
    o.x = fast_tanh(acc.x);
    o.y = fast_tanh(acc.y);
    o.z = fast_tanh(acc.z);
    o.w = fast_tanh(acc.w);

    // out slice base for (b, n, tq): contiguous 1 KB per wave
    float* op = out + ((size_t)(b * NN_ + n) * TT_ + tq * (TT_ / TQ_)) * CC_;
    ((float4*)op)[lane] = o;
}

extern "C" void kernel_launch(void* const* d_in, const int* in_sizes, int n_in,
                              void* d_out, int out_size, void* d_ws, size_t ws_size,
                              hipStream_t stream) {
    const float* z   = (const float*)d_in[0];
    const int*   nbr = (const int*)d_in[1];
    const float* adj = (const float*)d_in[2];
    const float* bw  = (const float*)d_in[3];
    const float* cc  = (const float*)d_in[4];
    float* out = (float*)d_out;
    unsigned short* zb16 = (unsigned short*)d_ws;   // 8 MB bf16 z

    z_to_bf16<<<dim3(BB_ * NN_ * PLANE_ / 8 / 256), dim3(256), 0, stream>>>(
        (const float4*)z, (uint4*)zb16);
    cgl_kernel<<<dim3(BB_ * TQ_ * (NN_ / NODES_PB)), dim3(256), 0, stream>>>(
        zb16, nbr, adj, bw, cc, out);
}

// Round 6
// 87.816 us; speedup vs baseline: 1.1941x; 1.0342x over previous
//
#include <hip/hip_runtime.h>

// CausalGraphLayer: out[b,n,t,c] = tanh( sum_k z[b, idx[n,k], t, c] * w[n,k,c] )
//   w[n,k,c] = adj[n,k] * sum_bb cc[c,bb] * bw[bb,n,k]
// B=2, N=2048, T=32, C=32, NBASE=4, MAXK=32, KC=16.
//
// R6: single kernel, best-of composition.
//  - R2 XCD-pinned (b,tq) t-quarter slices -> per-XCD gather set 2 MB (L2-resident)
//  - fp32 gather (no bf16 prepass: R5 showed prepass cost == gather saving)
//  - R4 scalar (SGPR) neighbor indices + all 16 gathers issued before the
//    w-compute barrier (loads in flight across __syncthreads)
//  - lean preamble: tables staged by disjoint thread ranges, no idx LDS trip

constexpr int BB_    = 2;
constexpr int NN_    = 2048;
constexpr int TT_    = 32;
constexpr int CC_    = 32;
constexpr int NBASE_ = 4;
constexpr int MAXK_  = 32;
constexpr int KC_    = 16;

constexpr int TQ_      = 4;                  // t-quarters
constexpr int NODES_PB = 4;                  // nodes per block (1 per wave)
constexpr int PLANE4_  = TT_ * CC_ / 4;      // 256 float4 per (b,n)
constexpr int SLICE4_  = (TT_ / TQ_) * CC_ / 4;  // 64 float4 per (n,tq)

__device__ __forceinline__ float fast_tanh(float x) {
    float e = __expf(2.0f * x);
    float r = __builtin_amdgcn_rcpf(e + 1.0f);
    return fmaf(-2.0f, r, 1.0f);
}

__global__ __launch_bounds__(256, 4) void cgl_kernel(
    const float* __restrict__ z,     // [B,N,T,C]
    const int*   __restrict__ nbr,   // [N,KC]
    const float* __restrict__ adj,   // [N,MAXK]
    const float* __restrict__ bw,    // [NBASE,N,MAXK]
    const float* __restrict__ cc,    // [C,NBASE]
    float*       __restrict__ out)   // [B,N,T,C]
{
    __shared__ __align__(16) float w_s[NODES_PB][KC_][CC_];  // 8 KB
    __shared__ float bw_s[NODES_PB][NBASE_][KC_];            // 1 KB
    __shared__ float cc_s[NBASE_][CC_];                      // 512 B (transposed)
    __shared__ float adj_s[NODES_PB][KC_];

    const int tid = threadIdx.x;
    const int blk = blockIdx.x;

    // XCD-pinned (b, tq): blk % 8 -> XCD round-robin.
    const int xcd   = blk & 7;
    const int b     = xcd >> 2;
    const int tq    = xcd & 3;
    const int group = blk >> 3;          // 0..511
    const int node0 = group * NODES_PB;

    const int wave = tid >> 6;
    const int lane = tid & 63;
    const int n    = node0 + wave;

    // ---- per-wave SGPR neighbor indices (block-uniform within wave) ----
    const int* __restrict__ ip = nbr + n * KC_;
    int nks[KC_];
    #pragma unroll
    for (int k = 0; k < KC_; ++k)
        nks[k] = __builtin_amdgcn_readfirstlane(ip[k]);

    // ---- issue ALL 16 fp32 gathers (1 KB / wave-instr, contiguous) ----
    float4 zv[KC_];
    {
        const float4* __restrict__ z4 =
            (const float4*)z + (size_t)b * NN_ * PLANE4_ + (size_t)tq * SLICE4_ + lane;
        #pragma unroll
        for (int k = 0; k < KC_; ++k)
            zv[k] = z4[(size_t)nks[k] * PLANE4_];
    }

    // ---- stage per-node tables into LDS (disjoint thread ranges) ----
    {   // bw: 256 values, one per thread
        int nd = tid >> 6, bb = (tid >> 4) & 3, k = tid & 15;
        bw_s[nd][bb][k] = bw[((size_t)bb * NN_ + (node0 + nd)) * MAXK_ + k];

        if (tid < 64) {                          // adj: node|k
            int nd2 = tid >> 4, k2 = tid & 15;
            adj_s[nd2][k2] = adj[(size_t)(node0 + nd2) * MAXK_ + k2];
        } else if (tid < 192) {                  // cc transposed [bb][c]
            int i = tid - 64, bb2 = i >> 5, c2 = i & 31;
            cc_s[bb2][c2] = cc[c2 * NBASE_ + bb2];
        }
    }
    __syncthreads();

    // ---- compute w[nd][k][c]: 2048 cells, 8 per thread ----
    {
        int i = tid;
        #pragma unroll
        for (int r = 0; r < 8; ++r, i += 256) {
            int nd = i >> 9, k = (i >> 5) & 15, c = i & 31;
            float s = cc_s[0][c] * bw_s[nd][0][k]
                    + cc_s[1][c] * bw_s[nd][1][k]
                    + cc_s[2][c] * bw_s[nd][2][k]
                    + cc_s[3][c] * bw_s[nd][3][k];
            w_s[nd][k][c] = s * adj_s[nd][k];
        }
    }
    __syncthreads();

    // ---- FMA reduction (zv loads drained by compiler waitcnt here) ----
    const int c0 = (lane << 2) & 31;
    float4 acc = make_float4(0.f, 0.f, 0.f, 0.f);
    #pragma unroll
    for (int k = 0; k < KC_; ++k) {
        float4 wv = *(const float4*)&w_s[wave][k][c0];   // 8-way broadcast, no conflict
        acc.x = fmaf(zv[k].x, wv.x, acc.x);
        acc.y = fmaf(zv[k].y, wv.y, acc.y);
        acc.z = fmaf(zv[k].z, wv.z, acc.z);
        acc.w = fmaf(zv[k].w, wv.w, acc.w);
    }

    float4 o;
    o.x = fast_tanh(acc.x);
    o.y = fast_tanh(acc.y);
    o.z = fast_tanh(acc.z);
    o.w = fast_tanh(acc.w);

    // contiguous 1 KB store per wave
    float4* op = (float4*)out + (size_t)(b * NN_ + n) * PLANE4_ + tq * SLICE4_;
    op[lane] = o;
}

extern "C" void kernel_launch(void* const* d_in, const int* in_sizes, int n_in,
                              void* d_out, int out_size, void* d_ws, size_t ws_size,
                              hipStream_t stream) {
    const float* z   = (const float*)d_in[0];
    const int*   nbr = (const int*)d_in[1];
    const float* adj = (const float*)d_in[2];
    const float* bw  = (const float*)d_in[3];
    const float* cc  = (const float*)d_in[4];
    float* out = (float*)d_out;

    cgl_kernel<<<dim3(BB_ * TQ_ * (NN_ / NODES_PB)), dim3(256), 0, stream>>>(
        z, nbr, adj, bw, cc, out);
}